// Round 5
// baseline (834.252 us; speedup 1.0000x reference)
//
#include <hip/hip_runtime.h>
#include <hip/hip_bf16.h>

// MoE MLP (top-2 of 8 experts), D=1024, FF=4096, 8192 tokens, fp32 in/out.
// router(+x->bf16) -> prefix -> cvt weights (bf16, [N][K]) -> grouped GEMMs.
// GEMM structure: 128x128 tile, BK=32, global_load_lds into linear [128][32]
// LDS, explicit 2-phase double-buffer: stage(t+1) issued BEFORE compute(t),
// ONE vmcnt(0)+barrier per K-step (T3-minimum recipe).

#define N_TOK 8192
#define DMODEL 1024
#define NEXP 8
#define DFF 4096
#define CAP 8192

typedef __attribute__((ext_vector_type(8))) short short8;
typedef __attribute__((ext_vector_type(4))) float f32x4;

#define GLOAD_LDS16(g, l)                                              \
  __builtin_amdgcn_global_load_lds(                                    \
      (const __attribute__((address_space(1))) unsigned int*)(g),      \
      (__attribute__((address_space(3))) unsigned int*)(l), 16, 0, 0)

__device__ __forceinline__ unsigned short f2bf(float f) {
  unsigned u = __float_as_uint(f);
  return (unsigned short)((u + 0x7FFFu + ((u >> 16) & 1u)) >> 16);  // RNE
}

__device__ __forceinline__ float gelu_f(float v) {
  return 0.5f * v * (1.0f + erff(v * 0.70710678118654752f));
}

__device__ __forceinline__ short8 pack8(float f0, float f1, float f2, float f3,
                                        float f4, float f5, float f6, float f7) {
  short8 r;
  r[0] = (short)f2bf(f0); r[1] = (short)f2bf(f1);
  r[2] = (short)f2bf(f2); r[3] = (short)f2bf(f3);
  r[4] = (short)f2bf(f4); r[5] = (short)f2bf(f5);
  r[6] = (short)f2bf(f6); r[7] = (short)f2bf(f7);
  return r;
}

// ---------------- Router: 1 wave per token (+ x -> bf16 copy) ----------------
__global__ void router_k(const float* __restrict__ x, const float* __restrict__ rw,
                         int* __restrict__ cnt, int* __restrict__ tok,
                         float* __restrict__ gate, unsigned short* __restrict__ xb) {
  int lane = threadIdx.x & 63;
  int t = blockIdx.x * 4 + (threadIdx.x >> 6);
  const float* xr = x + (size_t)t * DMODEL;
  unsigned short* xbr = xb + (size_t)t * DMODEL;
  float p[8];
#pragma unroll
  for (int e = 0; e < 8; ++e) p[e] = 0.0f;
#pragma unroll
  for (int j = 0; j < DMODEL / 64; ++j) {
    int i = lane + j * 64;
    float xv = xr[i];
    xbr[i] = f2bf(xv);
    const float4* r = (const float4*)(rw + (size_t)i * 8);
    float4 a = r[0], b = r[1];
    p[0] += xv * a.x; p[1] += xv * a.y; p[2] += xv * a.z; p[3] += xv * a.w;
    p[4] += xv * b.x; p[5] += xv * b.y; p[6] += xv * b.z; p[7] += xv * b.w;
  }
#pragma unroll
  for (int e = 0; e < 8; ++e) {
#pragma unroll
    for (int off = 32; off; off >>= 1) p[e] += __shfl_xor(p[e], off, 64);
  }
  if (lane == 0) {
    int e1 = 0;
#pragma unroll
    for (int e = 1; e < 8; ++e) if (p[e] > p[e1]) e1 = e;
    int e2 = (e1 == 0) ? 1 : 0;
#pragma unroll
    for (int e = 0; e < 8; ++e) if (e != e1 && p[e] > p[e2]) e2 = e;
    float w1 = 1.0f / (1.0f + expf(p[e2] - p[e1]));
    float w2 = 1.0f - w1;
    int s1 = atomicAdd(&cnt[e1], 1);
    tok[e1 * CAP + s1] = t; gate[e1 * CAP + s1] = w1;
    int s2 = atomicAdd(&cnt[e2], 1);
    tok[e2 * CAP + s2] = t; gate[e2 * CAP + s2] = w2;
  }
}

__global__ void prefix_k(const int* __restrict__ cnt, int* __restrict__ off) {
  if (threadIdx.x == 0 && blockIdx.x == 0) {
    int s = 0;
    for (int e = 0; e < NEXP; ++e) { off[e] = s; s += cnt[e]; }
  }
}

// W [E][K][N] fp32 -> WT [E][N][K] bf16 (64x64 tile LDS transpose)
__global__ __launch_bounds__(256) void cvt_wt_k(const float* __restrict__ W,
                                                unsigned short* __restrict__ WT,
                                                int K, int N) {
  __shared__ float ls[64][68];
  int b = blockIdx.x;
  int nkt = K >> 6, nnt = N >> 6;
  int kt = b % nkt;
  int nt = (b / nkt) % nnt;
  int e = b / (nkt * nnt);
  const float* Wb = W + (size_t)e * K * N + (size_t)(kt * 64) * N + nt * 64;
  int t = threadIdx.x;
  int nn = (t & 15) * 4, kr = t >> 4;
#pragma unroll
  for (int i = 0; i < 4; ++i) {
    float4 v = *(const float4*)(Wb + (size_t)(kr + 16 * i) * N + nn);
    *(float4*)&ls[kr + 16 * i][nn] = v;
  }
  __syncthreads();
  int on = t >> 2, kc = (t & 3) * 16;
  unsigned short* dst = WT + (size_t)e * N * K + (size_t)(nt * 64 + on) * K + kt * 64 + kc;
  short8 r0, r1;
#pragma unroll
  for (int j = 0; j < 8; ++j) r0[j] = (short)f2bf(ls[kc + j][on]);
#pragma unroll
  for (int j = 0; j < 8; ++j) r1[j] = (short)f2bf(ls[kc + 8 + j][on]);
  *(short8*)dst = r0;
  *(short8*)(dst + 8) = r1;
}

// Shared GEMM macros: stage one 128x32 K-tile pair into buf, compute from buf.
#define STAGE(buf, kk)                                              \
  do {                                                              \
    GLOAD_LDS16(gA0 + (kk), &As[buf][(w * 32 + lr) * 32 + lc]);     \
    GLOAD_LDS16(gA1 + (kk), &As[buf][(w * 32 + 16 + lr) * 32 + lc]);\
    GLOAD_LDS16(gB0 + (kk), &Bs[buf][(w * 32 + lr) * 32 + lc]);     \
    GLOAD_LDS16(gB1 + (kk), &Bs[buf][(w * 32 + 16 + lr) * 32 + lc]);\
  } while (0)

#define COMPUTE(buf)                                                            \
  do {                                                                          \
    short8 af[4], bfv[4];                                                       \
    _Pragma("unroll") for (int i = 0; i < 4; ++i)                               \
        af[i] = *(const short8*)&As[buf][(wr * 64 + i * 16 + fr) * 32 + g * 8]; \
    _Pragma("unroll") for (int i = 0; i < 4; ++i)                               \
        bfv[i] = *(const short8*)&Bs[buf][(wc * 64 + i * 16 + fr) * 32 + g * 8];\
    _Pragma("unroll") for (int mi = 0; mi < 4; ++mi)                            \
        _Pragma("unroll") for (int ni = 0; ni < 4; ++ni)                        \
            acc[mi][ni] = __builtin_amdgcn_mfma_f32_16x16x32_bf16(              \
                af[mi], bfv[ni], acc[mi][ni], 0, 0, 0);                         \
  } while (0)

#define SYNC()                                          \
  do {                                                  \
    asm volatile("s_waitcnt vmcnt(0)" ::: "memory");    \
    __syncthreads();                                    \
  } while (0)

// ---------------- GEMM1: h = gelu(Xb_gathered @ wfcT + bfc) ----------------
__global__ __launch_bounds__(256, 4) void gemm1a_k(
    const unsigned short* __restrict__ xb, const unsigned short* __restrict__ wT,
    const float* __restrict__ bfc, const int* __restrict__ cnt,
    const int* __restrict__ off, const int* __restrict__ tok,
    unsigned short* __restrict__ h) {
  int bid = (int)(blockIdx.x & 7) * ((int)gridDim.x >> 3) + (int)(blockIdx.x >> 3);
  int mt = bid & 63;
  int nt = (bid >> 6) & 31;
  int e = bid >> 11;
  int Me = cnt[e];
  if (mt * 128 >= Me) return;
  int base = off[e];
  int n0 = nt * 128;

  __shared__ __align__(16) unsigned short As[2][128 * 32];
  __shared__ __align__(16) unsigned short Bs[2][128 * 32];

  int tid = threadIdx.x;
  int lane = tid & 63, w = tid >> 6;
  int lr = lane >> 2;
  int lc = (lane & 3) * 8;

  int ar0i = mt * 128 + w * 32 + lr;
  int ar1i = ar0i + 16;
  int t0 = tok[e * CAP + ((ar0i < Me) ? ar0i : (Me - 1))];
  int t1 = tok[e * CAP + ((ar1i < Me) ? ar1i : (Me - 1))];
  const unsigned short* gA0 = xb + (size_t)t0 * DMODEL + lc;
  const unsigned short* gA1 = xb + (size_t)t1 * DMODEL + lc;
  const unsigned short* gB0 = wT + ((size_t)e * DFF + n0 + w * 32 + lr) * DMODEL + lc;
  const unsigned short* gB1 = gB0 + (size_t)16 * DMODEL;

  int wr = w >> 1, wc = w & 1;
  int g = lane >> 4, fr = lane & 15;

  f32x4 acc[4][4];
#pragma unroll
  for (int i = 0; i < 4; ++i)
#pragma unroll
    for (int j = 0; j < 4; ++j) acc[i][j] = (f32x4)0.0f;

  STAGE(0, 0);
  SYNC();
#pragma unroll 1
  for (int k0 = 0; k0 < DMODEL; k0 += 64) {
    STAGE(1, k0 + 32);          // stage tile t+1 (overlaps compute of t)
    COMPUTE(0);
    SYNC();
    if (k0 + 64 < DMODEL) STAGE(0, k0 + 64);  // stage tile t+2
    COMPUTE(1);
    SYNC();
  }

#pragma unroll
  for (int mi = 0; mi < 4; ++mi) {
    int rl = wr * 64 + mi * 16 + g * 4;
#pragma unroll
    for (int i = 0; i < 4; ++i) {
      int r = mt * 128 + rl + i;
      if (r < Me) {
        unsigned short* hrow = h + (size_t)(base + r) * DFF;
#pragma unroll
        for (int ni = 0; ni < 4; ++ni) {
          int col = n0 + wc * 64 + ni * 16 + fr;
          float v = acc[mi][ni][i] + bfc[e * DFF + col];
          hrow[col] = f2bf(gelu_f(v));
        }
      }
    }
  }
}

// ---------------- GEMM2: out += gate * (h @ wprojT + bproj) ----------------
__global__ __launch_bounds__(256, 4) void gemm2a_k(
    const unsigned short* __restrict__ h, const unsigned short* __restrict__ wT,
    const float* __restrict__ bproj, const int* __restrict__ cnt,
    const int* __restrict__ off, const int* __restrict__ tok,
    const float* __restrict__ gate, float* __restrict__ out) {
  int bid = (int)(blockIdx.x & 7) * ((int)gridDim.x >> 3) + (int)(blockIdx.x >> 3);
  int mt = bid & 63;
  int nt = (bid >> 6) & 7;
  int e = bid >> 9;
  int Me = cnt[e];
  if (mt * 128 >= Me) return;
  int base = off[e];
  int n0 = nt * 128;

  __shared__ __align__(16) unsigned short As[2][128 * 32];
  __shared__ __align__(16) unsigned short Bs[2][128 * 32];

  int tid = threadIdx.x;
  int lane = tid & 63, w = tid >> 6;
  int lr = lane >> 2;
  int lc = (lane & 3) * 8;

  // A rows beyond Me read following rows (in-bounds: h padded +128); masked at store.
  const unsigned short* gA0 = h + (size_t)(base + mt * 128 + w * 32 + lr) * DFF + lc;
  const unsigned short* gA1 = gA0 + (size_t)16 * DFF;
  const unsigned short* gB0 = wT + ((size_t)e * DMODEL + n0 + w * 32 + lr) * DFF + lc;
  const unsigned short* gB1 = gB0 + (size_t)16 * DFF;

  int wr = w >> 1, wc = w & 1;
  int g = lane >> 4, fr = lane & 15;

  f32x4 acc[4][4];
#pragma unroll
  for (int i = 0; i < 4; ++i)
#pragma unroll
    for (int j = 0; j < 4; ++j) acc[i][j] = (f32x4)0.0f;

  STAGE(0, 0);
  SYNC();
#pragma unroll 1
  for (int k0 = 0; k0 < DFF; k0 += 64) {
    STAGE(1, k0 + 32);
    COMPUTE(0);
    SYNC();
    if (k0 + 64 < DFF) STAGE(0, k0 + 64);
    COMPUTE(1);
    SYNC();
  }

#pragma unroll
  for (int mi = 0; mi < 4; ++mi) {
    int rl = wr * 64 + mi * 16 + g * 4;
#pragma unroll
    for (int i = 0; i < 4; ++i) {
      int r = mt * 128 + rl + i;
      if (r < Me) {
        int tkn = tok[e * CAP + r];
        float gv = gate[e * CAP + r];
        float* orow = out + (size_t)tkn * DMODEL;
#pragma unroll
        for (int ni = 0; ni < 4; ++ni) {
          int col = n0 + wc * 64 + ni * 16 + fr;
          float v = acc[mi][ni][i] + bproj[e * DMODEL + col];
          atomicAdd(orow + col, gv * v);
        }
      }
    }
  }
}

extern "C" void kernel_launch(void* const* d_in, const int* in_sizes, int n_in,
                              void* d_out, int out_size, void* d_ws, size_t ws_size,
                              hipStream_t stream) {
  const float* x = (const float*)d_in[0];
  const float* rw = (const float*)d_in[1];
  const float* wfc = (const float*)d_in[2];
  const float* bfc = (const float*)d_in[3];
  const float* wproj = (const float*)d_in[4];
  const float* bproj = (const float*)d_in[5];
  float* out = (float*)d_out;

  char* ws = (char*)d_ws;
  int* cnt = (int*)ws;
  int* off_ = (int*)(ws + 64);
  int* tok = (int*)(ws + 4096);
  float* gate = (float*)(ws + 4096 + (size_t)NEXP * CAP * 4);
  size_t HOFF = 4096 + 2 * (size_t)NEXP * CAP * 4;
  unsigned short* h = (unsigned short*)(ws + HOFF);
  size_t HSZ = (size_t)(16384 + 128) * DFF * 2;
  size_t XOFF = HOFF + HSZ;
  size_t WOFF = XOFF + (size_t)N_TOK * DMODEL * 2;
  unsigned short* xb = (unsigned short*)(ws + XOFF);
  unsigned short* wT = (unsigned short*)(ws + WOFF);  // reused: wfcT then wprojT

  hipMemsetAsync(cnt, 0, 128, stream);
  hipMemsetAsync(out, 0, (size_t)out_size * 4, stream);
  router_k<<<N_TOK / 4, 256, 0, stream>>>(x, rw, cnt, tok, gate, xb);
  prefix_k<<<1, 64, 0, stream>>>(cnt, off_);
  cvt_wt_k<<<NEXP * (DMODEL / 64) * (DFF / 64), 256, 0, stream>>>(wfc, wT, DMODEL, DFF);
  gemm1a_k<<<NEXP * 32 * 64, 256, 0, stream>>>(xb, wT, bfc, cnt, off_, tok, h);
  cvt_wt_k<<<NEXP * (DFF / 64) * (DMODEL / 64), 256, 0, stream>>>(wproj, wT, DFF, DMODEL);
  gemm2a_k<<<NEXP * 8 * 64, 256, 0, stream>>>(h, wT, bproj, cnt, off_, tok, gate, out);
}

// Round 6
// 797.444 us; speedup vs baseline: 1.0462x; 1.0462x over previous
//
#include <hip/hip_runtime.h>
#include <hip/hip_bf16.h>

// MoE MLP (top-2 of 8 experts), D=1024, FF=4096, 8192 tokens, fp32 in/out.
// router(+x->bf16) -> prefix -> cvt weights (bf16, [N][K]) -> grouped GEMMs.
// GEMM: 128x128 tile, BK=32, global_load_lds into linear [128][32] LDS,
// 2-deep prefetch with COUNTED vmcnt(4) (never drains to 0 in main loop),
// raw s_barrier (no implicit vmcnt(0) drain). T4 recipe.

#define N_TOK 8192
#define DMODEL 1024
#define NEXP 8
#define DFF 4096
#define CAP 8192

typedef __attribute__((ext_vector_type(8))) short short8;
typedef __attribute__((ext_vector_type(4))) float f32x4;

#define GLOAD_LDS16(g, l)                                              \
  __builtin_amdgcn_global_load_lds(                                    \
      (const __attribute__((address_space(1))) unsigned int*)(g),      \
      (__attribute__((address_space(3))) unsigned int*)(l), 16, 0, 0)

__device__ __forceinline__ unsigned short f2bf(float f) {
  unsigned u = __float_as_uint(f);
  return (unsigned short)((u + 0x7FFFu + ((u >> 16) & 1u)) >> 16);  // RNE
}

__device__ __forceinline__ float gelu_f(float v) {
  return 0.5f * v * (1.0f + erff(v * 0.70710678118654752f));
}

// ---------------- Router: 1 wave per token (+ x -> bf16 copy) ----------------
__global__ void router_k(const float* __restrict__ x, const float* __restrict__ rw,
                         int* __restrict__ cnt, int* __restrict__ tok,
                         float* __restrict__ gate, unsigned short* __restrict__ xb) {
  int lane = threadIdx.x & 63;
  int t = blockIdx.x * 4 + (threadIdx.x >> 6);
  const float* xr = x + (size_t)t * DMODEL;
  unsigned short* xbr = xb + (size_t)t * DMODEL;
  float p[8];
#pragma unroll
  for (int e = 0; e < 8; ++e) p[e] = 0.0f;
#pragma unroll
  for (int j = 0; j < DMODEL / 64; ++j) {
    int i = lane + j * 64;
    float xv = xr[i];
    xbr[i] = f2bf(xv);
    const float4* r = (const float4*)(rw + (size_t)i * 8);
    float4 a = r[0], b = r[1];
    p[0] += xv * a.x; p[1] += xv * a.y; p[2] += xv * a.z; p[3] += xv * a.w;
    p[4] += xv * b.x; p[5] += xv * b.y; p[6] += xv * b.z; p[7] += xv * b.w;
  }
#pragma unroll
  for (int e = 0; e < 8; ++e) {
#pragma unroll
    for (int off = 32; off; off >>= 1) p[e] += __shfl_xor(p[e], off, 64);
  }
  if (lane == 0) {
    int e1 = 0;
#pragma unroll
    for (int e = 1; e < 8; ++e) if (p[e] > p[e1]) e1 = e;
    int e2 = (e1 == 0) ? 1 : 0;
#pragma unroll
    for (int e = 0; e < 8; ++e) if (e != e1 && p[e] > p[e2]) e2 = e;
    float w1 = 1.0f / (1.0f + expf(p[e2] - p[e1]));
    float w2 = 1.0f - w1;
    int s1 = atomicAdd(&cnt[e1], 1);
    tok[e1 * CAP + s1] = t; gate[e1 * CAP + s1] = w1;
    int s2 = atomicAdd(&cnt[e2], 1);
    tok[e2 * CAP + s2] = t; gate[e2 * CAP + s2] = w2;
  }
}

__global__ void prefix_k(const int* __restrict__ cnt, int* __restrict__ off) {
  if (threadIdx.x == 0 && blockIdx.x == 0) {
    int s = 0;
    for (int e = 0; e < NEXP; ++e) { off[e] = s; s += cnt[e]; }
  }
}

// W [E][K][N] fp32 -> WT [E][N][K] bf16 (64x64 tile LDS transpose)
__global__ __launch_bounds__(256) void cvt_wt_k(const float* __restrict__ W,
                                                unsigned short* __restrict__ WT,
                                                int K, int N) {
  __shared__ float ls[64][68];
  int b = blockIdx.x;
  int nkt = K >> 6, nnt = N >> 6;
  int kt = b % nkt;
  int nt = (b / nkt) % nnt;
  int e = b / (nkt * nnt);
  const float* Wb = W + (size_t)e * K * N + (size_t)(kt * 64) * N + nt * 64;
  int t = threadIdx.x;
  int nn = (t & 15) * 4, kr = t >> 4;
#pragma unroll
  for (int i = 0; i < 4; ++i) {
    float4 v = *(const float4*)(Wb + (size_t)(kr + 16 * i) * N + nn);
    *(float4*)&ls[kr + 16 * i][nn] = v;
  }
  __syncthreads();
  int on = t >> 2, kc = (t & 3) * 16;
  unsigned short* dst = WT + (size_t)e * N * K + (size_t)(nt * 64 + on) * K + kt * 64 + kc;
  short8 r0, r1;
#pragma unroll
  for (int j = 0; j < 8; ++j) r0[j] = (short)f2bf(ls[kc + j][on]);
#pragma unroll
  for (int j = 0; j < 8; ++j) r1[j] = (short)f2bf(ls[kc + 8 + j][on]);
  *(short8*)dst = r0;
  *(short8*)(dst + 8) = r1;
}

// Stage one 128x32 K-tile pair (A+B) into buf: 4 global_load_lds per thread.
#define STAGE(buf, kk)                                              \
  do {                                                              \
    GLOAD_LDS16(gA0 + (kk), &As[buf][(w * 32 + lr) * 32 + lc]);     \
    GLOAD_LDS16(gA1 + (kk), &As[buf][(w * 32 + 16 + lr) * 32 + lc]);\
    GLOAD_LDS16(gB0 + (kk), &Bs[buf][(w * 32 + lr) * 32 + lc]);     \
    GLOAD_LDS16(gB1 + (kk), &Bs[buf][(w * 32 + 16 + lr) * 32 + lc]);\
  } while (0)

#define COMPUTE(buf)                                                            \
  do {                                                                          \
    short8 af[4], bfv[4];                                                       \
    _Pragma("unroll") for (int i = 0; i < 4; ++i)                               \
        af[i] = *(const short8*)&As[buf][(wr * 64 + i * 16 + fr) * 32 + g * 8]; \
    _Pragma("unroll") for (int i = 0; i < 4; ++i)                               \
        bfv[i] = *(const short8*)&Bs[buf][(wc * 64 + i * 16 + fr) * 32 + g * 8];\
    _Pragma("unroll") for (int mi = 0; mi < 4; ++mi)                            \
        _Pragma("unroll") for (int ni = 0; ni < 4; ++ni)                        \
            acc[mi][ni] = __builtin_amdgcn_mfma_f32_16x16x32_bf16(              \
                af[mi], bfv[ni], acc[mi][ni], 0, 0, 0);                         \
  } while (0)

#define WAITV(n) asm volatile("s_waitcnt vmcnt(" #n ")" ::: "memory")
#define BAR() __builtin_amdgcn_s_barrier()

// K-loop: 2-deep prefetch, counted vmcnt. At each wait, 8 loads outstanding:
// [cur tile's 4 (oldest), next tile's 4]; vmcnt(4) retires exactly cur's.
#define KLOOP(KTOT)                                                 \
  STAGE(0, 0);                                                      \
  STAGE(1, 32);                                                     \
  {                                                                 \
    int cur = 0;                                                    \
    _Pragma("unroll 1") for (int k0 = 0; k0 < (KTOT)-64; k0 += 32) {\
      WAITV(4);                                                     \
      BAR();                                                        \
      COMPUTE(cur);                                                 \
      BAR();                                                        \
      STAGE(cur, k0 + 64);                                          \
      cur ^= 1;                                                     \
    }                                                               \
    WAITV(4);                                                       \
    BAR();                                                          \
    COMPUTE(cur);                                                   \
    WAITV(0);                                                       \
    BAR();                                                          \
    COMPUTE(cur ^ 1);                                               \
  }

// ---------------- GEMM1: h = gelu(Xb_gathered @ wfcT + bfc) ----------------
__global__ __launch_bounds__(256, 4) void gemm1a_k(
    const unsigned short* __restrict__ xb, const unsigned short* __restrict__ wT,
    const float* __restrict__ bfc, const int* __restrict__ cnt,
    const int* __restrict__ off, const int* __restrict__ tok,
    unsigned short* __restrict__ h) {
  int bid = (int)(blockIdx.x & 7) * ((int)gridDim.x >> 3) + (int)(blockIdx.x >> 3);
  int mt = bid & 63;
  int nt = (bid >> 6) & 31;
  int e = bid >> 11;
  int Me = cnt[e];
  if (mt * 128 >= Me) return;
  int base = off[e];
  int n0 = nt * 128;

  __shared__ __align__(16) unsigned short As[2][128 * 32];
  __shared__ __align__(16) unsigned short Bs[2][128 * 32];

  int tid = threadIdx.x;
  int lane = tid & 63, w = tid >> 6;
  int lr = lane >> 2;
  int lc = (lane & 3) * 8;

  int ar0i = mt * 128 + w * 32 + lr;
  int ar1i = ar0i + 16;
  int t0 = tok[e * CAP + ((ar0i < Me) ? ar0i : (Me - 1))];
  int t1 = tok[e * CAP + ((ar1i < Me) ? ar1i : (Me - 1))];
  const unsigned short* gA0 = xb + (size_t)t0 * DMODEL + lc;
  const unsigned short* gA1 = xb + (size_t)t1 * DMODEL + lc;
  const unsigned short* gB0 = wT + ((size_t)e * DFF + n0 + w * 32 + lr) * DMODEL + lc;
  const unsigned short* gB1 = gB0 + (size_t)16 * DMODEL;

  int wr = w >> 1, wc = w & 1;
  int g = lane >> 4, fr = lane & 15;

  f32x4 acc[4][4];
#pragma unroll
  for (int i = 0; i < 4; ++i)
#pragma unroll
    for (int j = 0; j < 4; ++j) acc[i][j] = (f32x4)0.0f;

  KLOOP(DMODEL);

#pragma unroll
  for (int mi = 0; mi < 4; ++mi) {
    int rl = wr * 64 + mi * 16 + g * 4;
#pragma unroll
    for (int i = 0; i < 4; ++i) {
      int r = mt * 128 + rl + i;
      if (r < Me) {
        unsigned short* hrow = h + (size_t)(base + r) * DFF;
#pragma unroll
        for (int ni = 0; ni < 4; ++ni) {
          int col = n0 + wc * 64 + ni * 16 + fr;
          float v = acc[mi][ni][i] + bfc[e * DFF + col];
          hrow[col] = f2bf(gelu_f(v));
        }
      }
    }
  }
}

// ---------------- GEMM2: out += gate * (h @ wprojT + bproj) ----------------
__global__ __launch_bounds__(256, 4) void gemm2a_k(
    const unsigned short* __restrict__ h, const unsigned short* __restrict__ wT,
    const float* __restrict__ bproj, const int* __restrict__ cnt,
    const int* __restrict__ off, const int* __restrict__ tok,
    const float* __restrict__ gate, float* __restrict__ out) {
  int bid = (int)(blockIdx.x & 7) * ((int)gridDim.x >> 3) + (int)(blockIdx.x >> 3);
  int mt = bid & 63;
  int nt = (bid >> 6) & 7;
  int e = bid >> 9;
  int Me = cnt[e];
  if (mt * 128 >= Me) return;
  int base = off[e];
  int n0 = nt * 128;

  __shared__ __align__(16) unsigned short As[2][128 * 32];
  __shared__ __align__(16) unsigned short Bs[2][128 * 32];

  int tid = threadIdx.x;
  int lane = tid & 63, w = tid >> 6;
  int lr = lane >> 2;
  int lc = (lane & 3) * 8;

  // A rows beyond Me read following rows (in-bounds: h padded +128); masked at store.
  const unsigned short* gA0 = h + (size_t)(base + mt * 128 + w * 32 + lr) * DFF + lc;
  const unsigned short* gA1 = gA0 + (size_t)16 * DFF;
  const unsigned short* gB0 = wT + ((size_t)e * DMODEL + n0 + w * 32 + lr) * DFF + lc;
  const unsigned short* gB1 = gB0 + (size_t)16 * DFF;

  int wr = w >> 1, wc = w & 1;
  int g = lane >> 4, fr = lane & 15;

  f32x4 acc[4][4];
#pragma unroll
  for (int i = 0; i < 4; ++i)
#pragma unroll
    for (int j = 0; j < 4; ++j) acc[i][j] = (f32x4)0.0f;

  KLOOP(DFF);

#pragma unroll
  for (int mi = 0; mi < 4; ++mi) {
    int rl = wr * 64 + mi * 16 + g * 4;
#pragma unroll
    for (int i = 0; i < 4; ++i) {
      int r = mt * 128 + rl + i;
      if (r < Me) {
        int tkn = tok[e * CAP + r];
        float gv = gate[e * CAP + r];
        float* orow = out + (size_t)tkn * DMODEL;
#pragma unroll
        for (int ni = 0; ni < 4; ++ni) {
          int col = n0 + wc * 64 + ni * 16 + fr;
          float v = acc[mi][ni][i] + bproj[e * DMODEL + col];
          atomicAdd(orow + col, gv * v);
        }
      }
    }
  }
}

extern "C" void kernel_launch(void* const* d_in, const int* in_sizes, int n_in,
                              void* d_out, int out_size, void* d_ws, size_t ws_size,
                              hipStream_t stream) {
  const float* x = (const float*)d_in[0];
  const float* rw = (const float*)d_in[1];
  const float* wfc = (const float*)d_in[2];
  const float* bfc = (const float*)d_in[3];
  const float* wproj = (const float*)d_in[4];
  const float* bproj = (const float*)d_in[5];
  float* out = (float*)d_out;

  char* ws = (char*)d_ws;
  int* cnt = (int*)ws;
  int* off_ = (int*)(ws + 64);
  int* tok = (int*)(ws + 4096);
  float* gate = (float*)(ws + 4096 + (size_t)NEXP * CAP * 4);
  size_t HOFF = 4096 + 2 * (size_t)NEXP * CAP * 4;
  unsigned short* h = (unsigned short*)(ws + HOFF);
  size_t HSZ = (size_t)(16384 + 128) * DFF * 2;
  size_t XOFF = HOFF + HSZ;
  size_t WOFF = XOFF + (size_t)N_TOK * DMODEL * 2;
  unsigned short* xb = (unsigned short*)(ws + XOFF);
  unsigned short* wT = (unsigned short*)(ws + WOFF);  // reused: wfcT then wprojT

  hipMemsetAsync(cnt, 0, 128, stream);
  hipMemsetAsync(out, 0, (size_t)out_size * 4, stream);
  router_k<<<N_TOK / 4, 256, 0, stream>>>(x, rw, cnt, tok, gate, xb);
  prefix_k<<<1, 64, 0, stream>>>(cnt, off_);
  cvt_wt_k<<<NEXP * (DMODEL / 64) * (DFF / 64), 256, 0, stream>>>(wfc, wT, DMODEL, DFF);
  gemm1a_k<<<NEXP * 32 * 64, 256, 0, stream>>>(xb, wT, bfc, cnt, off_, tok, h);
  cvt_wt_k<<<NEXP * (DFF / 64) * (DMODEL / 64), 256, 0, stream>>>(wproj, wT, DFF, DMODEL);
  gemm2a_k<<<NEXP * 8 * 64, 256, 0, stream>>>(h, wT, bproj, cnt, off_, tok, gate, out);
}